// Round 6
// baseline (7731.997 us; speedup 1.0000x reference)
//
#include <hip/hip_runtime.h>
#include <hip/hip_bf16.h>

using u16 = unsigned short;
using u32 = unsigned int;
using u64 = unsigned long long;

typedef __attribute__((ext_vector_type(8))) short bf16x8;
typedef __attribute__((ext_vector_type(4))) float f32x4;

#define MFMA_BF16 __builtin_amdgcn_mfma_f32_16x16x32_bf16

// T=512, B=64, H=1024, 3H=3072
// ws layout (bytes):
//   xb/out0 @ 0         : 67108864   (x as bf16 [32768][1024]; later layer-0 output)
//   gx      @ 67108864  : 201326592  (input proj, bf16, layout [t][jb][gate][b][jr])
//   wb      @ 268435456 : 25165824   (w_ih0|w_hh0|w_ih1|w_hh1 bf16 row-major)
//   hb0     @ 293601280 : 262144     (layer-0 h ping-pong, fragment layout)
//   hb1     @ 293863424 : 262144     (layer-1 h ping-pong)
//   bar     @ 294125568 : 256        (barrier counters, u32; slot0=L0 slot32=L1)
// total 294125824

static __device__ __forceinline__ u16 f2bf(float f) {
  union { float f; u32 u; } v; v.f = f;
  u32 r = v.u + 0x7FFFu + ((v.u >> 16) & 1u);   // RTNE
  return (u16)(r >> 16);
}
static __device__ __forceinline__ float bf2f(u16 u) {
  union { u32 u; float f; } v; v.u = ((u32)u) << 16; return v.f;
}

// Fragment-layout offset (u16 elements) of h[b][j] inside a 64x1024 buffer.
// Layout: [rt=b>>4][ks=j>>5][lane=(j>>3&3)<<4 | (b&15)][e=j&7]
static __device__ __forceinline__ int fragoff(int b, int j) {
  return ((b >> 4) << 14) | ((j >> 5) << 9) |
         (((((j >> 3) & 3) << 4) | (b & 15)) << 3) | (j & 7);
}

// gx scan-friendly layout offset (elements): [t][jb=j>>4][gate][b][jr=j&15]
static __device__ __forceinline__ size_t gxoff(int t, int jb, int gate, int b, int jr) {
  return (((size_t)t * 64 + jb) * 3 + gate) * 1024 + b * 16 + jr;
}

// LLC-coherent (agent-scope) accessors for the h exchange: performed at the
// agent coherence point, so no wbl2/inv fences are needed at the barrier.
static __device__ __forceinline__ void h_store(u16* p, u16 v) {
  __hip_atomic_store(p, v, __ATOMIC_RELAXED, __HIP_MEMORY_SCOPE_AGENT);
}
static __device__ __forceinline__ u16 h_load16(const u16* p) {
  return __hip_atomic_load(p, __ATOMIC_RELAXED, __HIP_MEMORY_SCOPE_AGENT);
}
static __device__ __forceinline__ bf16x8 h_load128(const u16* p) {
  union { u64 q[2]; bf16x8 v; } u_;
  u_.q[0] = __hip_atomic_load((const u64*)p, __ATOMIC_RELAXED, __HIP_MEMORY_SCOPE_AGENT);
  u_.q[1] = __hip_atomic_load((const u64*)p + 1, __ATOMIC_RELAXED, __HIP_MEMORY_SCOPE_AGENT);
  return u_.v;
}

// ---------------------------------------------------------------- convert ---
__global__ void convert_kernel(const float* __restrict__ x,
                               const float* __restrict__ w0, const float* __restrict__ w1,
                               const float* __restrict__ w2, const float* __restrict__ w3,
                               const float* __restrict__ h0,
                               u16* __restrict__ xb, u16* __restrict__ wout,
                               u16* __restrict__ hb0, u16* __restrict__ hb1,
                               u32* __restrict__ bar)
{
  const int nt = gridDim.x * blockDim.x;
  const int t0 = blockIdx.x * blockDim.x + threadIdx.x;

  if (t0 < 64) bar[t0] = 0;   // zero barrier counters (ws is poisoned each launch)

  // x: 33554432 floats = 8388608 float4
  for (int i = t0; i < 8388608; i += nt) {
    float4 v = ((const float4*)x)[i];
    ushort4 o; o.x = f2bf(v.x); o.y = f2bf(v.y); o.z = f2bf(v.z); o.w = f2bf(v.w);
    ((ushort4*)xb)[i] = o;
  }
  // weights: 4 x 3145728 floats = 4 x 786432 float4
  for (int i = t0; i < 786432; i += nt) {
    float4 v; ushort4 o;
    v = ((const float4*)w0)[i];
    o.x = f2bf(v.x); o.y = f2bf(v.y); o.z = f2bf(v.z); o.w = f2bf(v.w);
    ((ushort4*)(wout + 0))[i] = o;
    v = ((const float4*)w1)[i];
    o.x = f2bf(v.x); o.y = f2bf(v.y); o.z = f2bf(v.z); o.w = f2bf(v.w);
    ((ushort4*)(wout + 3145728))[i] = o;
    v = ((const float4*)w2)[i];
    o.x = f2bf(v.x); o.y = f2bf(v.y); o.z = f2bf(v.z); o.w = f2bf(v.w);
    ((ushort4*)(wout + 6291456))[i] = o;
    v = ((const float4*)w3)[i];
    o.x = f2bf(v.x); o.y = f2bf(v.y); o.z = f2bf(v.z); o.w = f2bf(v.w);
    ((ushort4*)(wout + 9437184))[i] = o;
  }
  // h0: (2, 64, 1024) -> fragment layout per layer
  for (int e = t0; e < 131072; e += nt) {
    const int l = e >> 16; const int rem = e & 65535;
    const int b = rem >> 10; const int j = rem & 1023;
    (l ? hb1 : hb0)[fragoff(b, j)] = f2bf(h0[e]);
  }
}

// ------------------------------------------------------------------- GEMM ---
// gx[gxoff(t,jb,gate,b,jr)] = sum_k A[t*64+b][k]*W[gate*1024+j][k] + bias
// A: Mx1024 bf16 row-major, W: 3072x1024 bf16 row-major.
// 128x128 tile, BK=64, 4 waves (2x2), m97-style global_load_lds staging.
__global__ __launch_bounds__(256) void gemm_bt_bias(
    const u16* __restrict__ A, const u16* __restrict__ W,
    const float* __restrict__ bias, u16* __restrict__ C)
{
  __shared__ u16 As[128 * 64];
  __shared__ u16 Bs[128 * 64];
  const int tid = threadIdx.x;
  const int lane = tid & 63;
  const int wave = tid >> 6;
  const int wr = wave >> 1, wc = wave & 1;
  const int bm = blockIdx.x, bn = blockIdx.y;

  f32x4 acc[4][4];
  #pragma unroll
  for (int mr = 0; mr < 4; ++mr)
    #pragma unroll
    for (int nc = 0; nc < 4; ++nc)
      acc[mr][nc] = (f32x4){0.f, 0.f, 0.f, 0.f};

  const u16* Ab = A + ((size_t)bm * 128) * 1024;
  const u16* Wb = W + ((size_t)bn * 128) * 1024;
  const int rbase = wave * 8 + (lane >> 3);     // row within 32-row stripe
  const int celem = (lane & 7) * 8;             // 16B chunk within 64-col row

  for (int kt = 0; kt < 16; ++kt) {
    __syncthreads();                            // protect LDS from previous reads
    #pragma unroll
    for (int i = 0; i < 4; ++i) {
      const u16* gA = Ab + (size_t)(i * 32 + rbase) * 1024 + kt * 64 + celem;
      const u16* gB = Wb + (size_t)(i * 32 + rbase) * 1024 + kt * 64 + celem;
      __builtin_amdgcn_global_load_lds(
          (const __attribute__((address_space(1))) void*)gA,
          (__attribute__((address_space(3))) void*)(As + (i * 32 + wave * 8) * 64), 16, 0, 0);
      __builtin_amdgcn_global_load_lds(
          (const __attribute__((address_space(1))) void*)gB,
          (__attribute__((address_space(3))) void*)(Bs + (i * 32 + wave * 8) * 64), 16, 0, 0);
    }
    __syncthreads();                            // drains vmcnt (staging complete)
    #pragma unroll
    for (int ks = 0; ks < 2; ++ks) {
      bf16x8 af[4], bf_[4];
      #pragma unroll
      for (int mr = 0; mr < 4; ++mr)
        af[mr] = *(const bf16x8*)(As + (wr * 64 + mr * 16 + (lane & 15)) * 64 +
                                  ks * 32 + ((lane >> 4) << 3));
      #pragma unroll
      for (int nc = 0; nc < 4; ++nc)
        bf_[nc] = *(const bf16x8*)(Bs + (wc * 64 + nc * 16 + (lane & 15)) * 64 +
                                   ks * 32 + ((lane >> 4) << 3));
      #pragma unroll
      for (int mr = 0; mr < 4; ++mr)
        #pragma unroll
        for (int nc = 0; nc < 4; ++nc)
          acc[mr][nc] = MFMA_BF16(af[mr], bf_[nc], acc[mr][nc], 0, 0, 0);
    }
  }
  // epilogue: D col(n) = lane&15, row(m) = (lane>>4)*4+reg
  #pragma unroll
  for (int nc = 0; nc < 4; ++nc) {
    const int n = bn * 128 + wc * 64 + nc * 16 + (lane & 15);
    const int gate = n >> 10, jb = (n & 1023) >> 4, jr = n & 15;
    const float bv = bias[n];
    #pragma unroll
    for (int mr = 0; mr < 4; ++mr) {
      const int m0 = bm * 128 + wr * 64 + mr * 16 + ((lane >> 4) << 2);
      const int t = m0 >> 6, b0 = m0 & 63;
      #pragma unroll
      for (int r = 0; r < 4; ++r)
        C[gxoff(t, jb, gate, b0 + r, jr)] = f2bf(acc[mr][nc][r] + bv);
    }
  }
}

// ------------------------------------------------------------------- scan ---
// Persistent GRU scan, PLAIN launch (no cooperative API): 64 WGs x 4 waves,
// one WG per CU (96KB LDS, launch_bounds(256,1)), grid 64 << 256 CUs and the
// scan runs on an idle device (stream-ordered after GEMM), so all blocks are
// co-resident. h is exchanged through the LLC via agent-scope relaxed
// atomics; the per-step barrier is a fence-free monotonic counter.
template <int LAYER>
__global__ __launch_bounds__(256, 1) void scan_kernel(
    const u16* __restrict__ gx,    // gxoff layout (b_ih folded in)
    const u16* __restrict__ whh,   // [3072*1024] bf16 row-major
    const float* __restrict__ bhh, // [3072] fp32
    u16* __restrict__ hbuf,        // [2*65536] fragment layout (ping=idx0 init)
    u16* __restrict__ out_bf,      // LAYER==0: out0 bf16 row-major
    float* __restrict__ out_f,     // LAYER==1: d_out fp32
    float* __restrict__ hN,        // final h (fp32, 64*1024)
    u32* __restrict__ bar)         // barrier counter (zeroed by convert)
{
  extern __shared__ u16 wlds[];    // 49152 u16 = 96 KB
  const int tid = threadIdx.x;
  const int lane = tid & 63;
  const int wave = tid >> 6;       // row-tile (16 batch rows)
  const int bx = blockIdx.x;
  const int jbase = bx * 16;
  const int jr = lane & 15;

  // ---- one-time: W_hh slice -> LDS in fragment order ----
  #pragma unroll
  for (int u = 0; u < 24; ++u) {
    const int idx = wave * 24 + u;           // 0..95 = ct*32+ks
    const int ct = idx >> 5, ks = idx & 31;
    const int wrow = ct * 1024 + jbase + jr;
    const int k = ks * 32 + ((lane >> 4) << 3);
    *(bf16x8*)(wlds + idx * 512 + lane * 8) =
        *(const bf16x8*)(whh + (size_t)wrow * 1024 + k);
  }
  __syncthreads();

  const int j = jbase + jr;
  const float bias_r = bhh[j], bias_z = bhh[1024 + j], bias_n = bhh[2048 + j];

  // gx register prefetch for step t (h-independent, loaded pre-barrier)
  float pxr[4], pxz[4], pxn[4];
  {
    const u16* g = gx + gxoff(0, bx, 0, 0, 0);
    #pragma unroll
    for (int r = 0; r < 4; ++r) {
      const int b = wave * 16 + ((lane >> 4) << 2) + r;
      pxr[r] = bf2f(g[b * 16 + jr]);
      pxz[r] = bf2f(g[1024 + b * 16 + jr]);
      pxn[r] = bf2f(g[2048 + b * 16 + jr]);
    }
  }

  int p = 0;
  for (int t = 0; t < 512; ++t) {
    const u16* hsrc = hbuf + p * 65536;
    const u16* ab = hsrc + wave * 16384 + lane * 8;
    bf16x8 a[32];
    #pragma unroll
    for (int ks = 0; ks < 32; ++ks)
      a[ks] = h_load128(ab + ks * 512);          // coherent 16B loads (LLC)

    // issue the gate-epilogue's h re-reads early (off the post-MFMA path)
    float ho[4];
    #pragma unroll
    for (int r = 0; r < 4; ++r) {
      const int b = wave * 16 + ((lane >> 4) << 2) + r;
      ho[r] = bf2f(h_load16(hsrc + fragoff(b, j)));
    }

    f32x4 accr = {0.f, 0.f, 0.f, 0.f};
    f32x4 accz = accr, accn = accr;
    #pragma unroll
    for (int ks = 0; ks < 32; ++ks) {
      bf16x8 b0 = *(const bf16x8*)(wlds + ks * 512 + lane * 8);
      bf16x8 b1 = *(const bf16x8*)(wlds + (32 + ks) * 512 + lane * 8);
      bf16x8 b2 = *(const bf16x8*)(wlds + (64 + ks) * 512 + lane * 8);
      accr = MFMA_BF16(a[ks], b0, accr, 0, 0, 0);
      accz = MFMA_BF16(a[ks], b1, accz, 0, 0, 0);
      accn = MFMA_BF16(a[ks], b2, accn, 0, 0, 0);
    }

    // gates: acc{r,z,n}[r] all live at the same (b, j) per D-layout.
    u16* hdst = hbuf + (p ^ 1) * 65536;
    #pragma unroll
    for (int r = 0; r < 4; ++r) {
      const int b = wave * 16 + ((lane >> 4) << 2) + r;
      const float rg = 1.f / (1.f + __expf(-(pxr[r] + accr[r] + bias_r)));
      const float zg = 1.f / (1.f + __expf(-(pxz[r] + accz[r] + bias_z)));
      const float ng = tanhf(pxn[r] + rg * (accn[r] + bias_n));
      const float hv = (1.f - zg) * ng + zg * ho[r];
      const u16 hu = f2bf(hv);
      h_store(hdst + fragoff(b, j), hu);         // coherent store (LLC)
      const size_t orow = (size_t)t * 64 + b;
      if (LAYER == 0) __builtin_nontemporal_store(hu, out_bf + orow * 1024 + j);
      else            __builtin_nontemporal_store(hv, out_f + orow * 1024 + j);
      if (t == 511) __builtin_nontemporal_store(hv, hN + b * 1024 + j);
    }

    // prefetch gx for step t+1 into registers (independent of the barrier)
    if (t < 511) {
      const u16* g = gx + gxoff(t + 1, bx, 0, 0, 0);
      #pragma unroll
      for (int r = 0; r < 4; ++r) {
        const int b = wave * 16 + ((lane >> 4) << 2) + r;
        pxr[r] = bf2f(g[b * 16 + jr]);
        pxz[r] = bf2f(g[1024 + b * 16 + jr]);
        pxn[r] = bf2f(g[2048 + b * 16 + jr]);
      }
    }

    // ---- fence-free grid barrier (h traffic is already LLC-coherent) ----
    asm volatile("s_waitcnt vmcnt(0)" ::: "memory");  // own stores performed
    __syncthreads();   // all waves drained, then s_barrier
    if (tid == 0) {
      __hip_atomic_fetch_add(bar, 1u, __ATOMIC_RELAXED, __HIP_MEMORY_SCOPE_AGENT);
      const u32 tgt = 64u * (u32)(t + 1);
      while (__hip_atomic_load(bar, __ATOMIC_RELAXED, __HIP_MEMORY_SCOPE_AGENT) < tgt)
        __builtin_amdgcn_s_sleep(1);
    }
    __syncthreads();
    p ^= 1;
  }
}

// ----------------------------------------------------------------- launch ---
extern "C" void kernel_launch(void* const* d_in, const int* in_sizes, int n_in,
                              void* d_out, int out_size, void* d_ws, size_t ws_size,
                              hipStream_t stream)
{
  const float* x     = (const float*)d_in[0];
  const float* h0    = (const float*)d_in[1];
  const float* w_ih0 = (const float*)d_in[2];
  const float* w_hh0 = (const float*)d_in[3];
  const float* b_ih0 = (const float*)d_in[4];
  const float* b_hh0 = (const float*)d_in[5];
  const float* w_ih1 = (const float*)d_in[6];
  const float* w_hh1 = (const float*)d_in[7];
  const float* b_ih1 = (const float*)d_in[8];
  const float* b_hh1 = (const float*)d_in[9];

  if (ws_size < 294125824ull) return;   // insufficient scratch -> fail visibly

  char* ws = (char*)d_ws;
  u16* xb   = (u16*)(ws + 0);           // x bf16; later reused as out0
  u16* out0 = xb;                       // alias: xb dead after first GEMM
  u16* gx   = (u16*)(ws + 67108864);
  u16* wb   = (u16*)(ws + 268435456);
  u16* hb0  = (u16*)(ws + 293601280);
  u16* hb1  = (u16*)(ws + 293863424);
  u32* bar  = (u32*)(ws + 294125568);

  float* out1 = (float*)d_out;
  float* hN0  = out1 + 33554432;        // h_n[0]
  float* hN1  = hN0 + 65536;            // h_n[1]

  u16* wb_ih0 = wb;
  u16* wb_hh0 = wb + 3145728;
  u16* wb_ih1 = wb + 6291456;
  u16* wb_hh1 = wb + 9437184;

  hipLaunchKernelGGL(convert_kernel, dim3(1024), dim3(256), 0, stream,
                     x, w_ih0, w_hh0, w_ih1, w_hh1, h0, xb, wb, hb0, hb1, bar);

  dim3 gg(256, 24);
  hipLaunchKernelGGL(gemm_bt_bias, gg, dim3(256), 0, stream, xb, wb_ih0, b_ih0, gx);

  hipFuncSetAttribute(reinterpret_cast<const void*>(&scan_kernel<0>),
                      hipFuncAttributeMaxDynamicSharedMemorySize, 98304);
  hipFuncSetAttribute(reinterpret_cast<const void*>(&scan_kernel<1>),
                      hipFuncAttributeMaxDynamicSharedMemorySize, 98304);

  hipLaunchKernelGGL(scan_kernel<0>, dim3(64), dim3(256), 98304, stream,
                     (const u16*)gx, (const u16*)wb_hh0, b_hh0,
                     hb0, out0, (float*)nullptr, hN0, bar);

  hipLaunchKernelGGL(gemm_bt_bias, gg, dim3(256), 0, stream, out0, wb_ih1, b_ih1, gx);

  hipLaunchKernelGGL(scan_kernel<1>, dim3(64), dim3(256), 98304, stream,
                     (const u16*)gx, (const u16*)wb_hh1, b_hh1,
                     hb1, (u16*)nullptr, out1, hN1, bar + 32);
}

// Round 9
// 7559.837 us; speedup vs baseline: 1.0228x; 1.0228x over previous
//
#include <hip/hip_runtime.h>
#include <hip/hip_bf16.h>

using u16 = unsigned short;
using u32 = unsigned int;
using u64 = unsigned long long;

typedef __attribute__((ext_vector_type(8))) short bf16x8;
typedef __attribute__((ext_vector_type(4))) float f32x4;

#define MFMA_BF16 __builtin_amdgcn_mfma_f32_16x16x32_bf16

// T=512, B=64, H=1024, 3H=3072
// ws layout (bytes):
//   xb/out0 @ 0         : 67108864   (x as bf16 [32768][1024]; later layer-0 output)
//   gx      @ 67108864  : 201326592  (input proj, bf16, layout [t][jb][gate][b][jr])
//   wb      @ 268435456 : 25165824   (w_ih0|w_hh0|w_ih1|w_hh1 bf16 row-major)
//   hb0     @ 293601280 : 262144     (layer-0 h ping-pong, fragment layout)
//   hb1     @ 293863424 : 262144     (layer-1 h ping-pong)
//   bar     @ 294125568 : 256        (barrier counters, u32; slot0=L0 slot32=L1)
// total 294125824

static __device__ __forceinline__ u16 f2bf(float f) {
  union { float f; u32 u; } v; v.f = f;
  u32 r = v.u + 0x7FFFu + ((v.u >> 16) & 1u);   // RTNE
  return (u16)(r >> 16);
}
static __device__ __forceinline__ float bf2f(u16 u) {
  union { u32 u; float f; } v; v.u = ((u32)u) << 16; return v.f;
}

// Fragment-layout offset (u16 elements) of h[b][j] inside a 64x1024 buffer.
// Layout: [rt=b>>4][ks=j>>5][lane=(j>>3&3)<<4 | (b&15)][e=j&7]
static __device__ __forceinline__ int fragoff(int b, int j) {
  return ((b >> 4) << 14) | ((j >> 5) << 9) |
         (((((j >> 3) & 3) << 4) | (b & 15)) << 3) | (j & 7);
}

// gx scan-friendly layout offset (elements): [t][jb=j>>4][gate][b][jr=j&15]
static __device__ __forceinline__ size_t gxoff(int t, int jb, int gate, int b, int jr) {
  return (((size_t)t * 64 + jb) * 3 + gate) * 1024 + b * 16 + jr;
}

// LLC-coherent (agent-scope) accessors for the h exchange: performed at the
// agent coherence point, so no wbl2/inv fences are needed at the barrier.
static __device__ __forceinline__ void h_store(u16* p, u16 v) {
  __hip_atomic_store(p, v, __ATOMIC_RELAXED, __HIP_MEMORY_SCOPE_AGENT);
}
static __device__ __forceinline__ u16 h_load16(const u16* p) {
  return __hip_atomic_load(p, __ATOMIC_RELAXED, __HIP_MEMORY_SCOPE_AGENT);
}
static __device__ __forceinline__ bf16x8 h_load128(const u16* p) {
  union { u64 q[2]; bf16x8 v; } u_;
  u_.q[0] = __hip_atomic_load((const u64*)p, __ATOMIC_RELAXED, __HIP_MEMORY_SCOPE_AGENT);
  u_.q[1] = __hip_atomic_load((const u64*)p + 1, __ATOMIC_RELAXED, __HIP_MEMORY_SCOPE_AGENT);
  return u_.v;
}

// ---------------------------------------------------------------- convert ---
__global__ void convert_kernel(const float* __restrict__ x,
                               const float* __restrict__ w0, const float* __restrict__ w1,
                               const float* __restrict__ w2, const float* __restrict__ w3,
                               const float* __restrict__ h0,
                               u16* __restrict__ xb, u16* __restrict__ wout,
                               u16* __restrict__ hb0, u16* __restrict__ hb1,
                               u32* __restrict__ bar)
{
  const int nt = gridDim.x * blockDim.x;
  const int t0 = blockIdx.x * blockDim.x + threadIdx.x;

  if (t0 < 64) bar[t0] = 0;   // zero barrier counters (ws is poisoned each launch)

  // x: 33554432 floats = 8388608 float4
  for (int i = t0; i < 8388608; i += nt) {
    float4 v = ((const float4*)x)[i];
    ushort4 o; o.x = f2bf(v.x); o.y = f2bf(v.y); o.z = f2bf(v.z); o.w = f2bf(v.w);
    ((ushort4*)xb)[i] = o;
  }
  // weights: 4 x 3145728 floats = 4 x 786432 float4
  for (int i = t0; i < 786432; i += nt) {
    float4 v; ushort4 o;
    v = ((const float4*)w0)[i];
    o.x = f2bf(v.x); o.y = f2bf(v.y); o.z = f2bf(v.z); o.w = f2bf(v.w);
    ((ushort4*)(wout + 0))[i] = o;
    v = ((const float4*)w1)[i];
    o.x = f2bf(v.x); o.y = f2bf(v.y); o.z = f2bf(v.z); o.w = f2bf(v.w);
    ((ushort4*)(wout + 3145728))[i] = o;
    v = ((const float4*)w2)[i];
    o.x = f2bf(v.x); o.y = f2bf(v.y); o.z = f2bf(v.z); o.w = f2bf(v.w);
    ((ushort4*)(wout + 6291456))[i] = o;
    v = ((const float4*)w3)[i];
    o.x = f2bf(v.x); o.y = f2bf(v.y); o.z = f2bf(v.z); o.w = f2bf(v.w);
    ((ushort4*)(wout + 9437184))[i] = o;
  }
  // h0: (2, 64, 1024) -> fragment layout per layer
  for (int e = t0; e < 131072; e += nt) {
    const int l = e >> 16; const int rem = e & 65535;
    const int b = rem >> 10; const int j = rem & 1023;
    (l ? hb1 : hb0)[fragoff(b, j)] = f2bf(h0[e]);
  }
}

// ------------------------------------------------------------------- GEMM ---
// gx[gxoff(t,jb,gate,b,jr)] = sum_k A[t*64+b][k]*W[gate*1024+j][k] + bias
// A: Mx1024 bf16 row-major, W: 3072x1024 bf16 row-major.
// 128x128 tile, BK=64, 4 waves (2x2), m97-style global_load_lds staging.
__global__ __launch_bounds__(256) void gemm_bt_bias(
    const u16* __restrict__ A, const u16* __restrict__ W,
    const float* __restrict__ bias, u16* __restrict__ C)
{
  __shared__ u16 As[128 * 64];
  __shared__ u16 Bs[128 * 64];
  const int tid = threadIdx.x;
  const int lane = tid & 63;
  const int wave = tid >> 6;
  const int wr = wave >> 1, wc = wave & 1;
  const int bm = blockIdx.x, bn = blockIdx.y;

  f32x4 acc[4][4];
  #pragma unroll
  for (int mr = 0; mr < 4; ++mr)
    #pragma unroll
    for (int nc = 0; nc < 4; ++nc)
      acc[mr][nc] = (f32x4){0.f, 0.f, 0.f, 0.f};

  const u16* Ab = A + ((size_t)bm * 128) * 1024;
  const u16* Wb = W + ((size_t)bn * 128) * 1024;
  const int rbase = wave * 8 + (lane >> 3);     // row within 32-row stripe
  const int celem = (lane & 7) * 8;             // 16B chunk within 64-col row

  for (int kt = 0; kt < 16; ++kt) {
    __syncthreads();                            // protect LDS from previous reads
    #pragma unroll
    for (int i = 0; i < 4; ++i) {
      const u16* gA = Ab + (size_t)(i * 32 + rbase) * 1024 + kt * 64 + celem;
      const u16* gB = Wb + (size_t)(i * 32 + rbase) * 1024 + kt * 64 + celem;
      __builtin_amdgcn_global_load_lds(
          (const __attribute__((address_space(1))) void*)gA,
          (__attribute__((address_space(3))) void*)(As + (i * 32 + wave * 8) * 64), 16, 0, 0);
      __builtin_amdgcn_global_load_lds(
          (const __attribute__((address_space(1))) void*)gB,
          (__attribute__((address_space(3))) void*)(Bs + (i * 32 + wave * 8) * 64), 16, 0, 0);
    }
    __syncthreads();                            // drains vmcnt (staging complete)
    #pragma unroll
    for (int ks = 0; ks < 2; ++ks) {
      bf16x8 af[4], bf_[4];
      #pragma unroll
      for (int mr = 0; mr < 4; ++mr)
        af[mr] = *(const bf16x8*)(As + (wr * 64 + mr * 16 + (lane & 15)) * 64 +
                                  ks * 32 + ((lane >> 4) << 3));
      #pragma unroll
      for (int nc = 0; nc < 4; ++nc)
        bf_[nc] = *(const bf16x8*)(Bs + (wc * 64 + nc * 16 + (lane & 15)) * 64 +
                                   ks * 32 + ((lane >> 4) << 3));
      #pragma unroll
      for (int mr = 0; mr < 4; ++mr)
        #pragma unroll
        for (int nc = 0; nc < 4; ++nc)
          acc[mr][nc] = MFMA_BF16(af[mr], bf_[nc], acc[mr][nc], 0, 0, 0);
    }
  }
  // epilogue: D col(n) = lane&15, row(m) = (lane>>4)*4+reg
  #pragma unroll
  for (int nc = 0; nc < 4; ++nc) {
    const int n = bn * 128 + wc * 64 + nc * 16 + (lane & 15);
    const int gate = n >> 10, jb = (n & 1023) >> 4, jr = n & 15;
    const float bv = bias[n];
    #pragma unroll
    for (int mr = 0; mr < 4; ++mr) {
      const int m0 = bm * 128 + wr * 64 + mr * 16 + ((lane >> 4) << 2);
      const int t = m0 >> 6, b0 = m0 & 63;
      #pragma unroll
      for (int r = 0; r < 4; ++r)
        C[gxoff(t, jb, gate, b0 + r, jr)] = f2bf(acc[mr][nc][r] + bv);
    }
  }
}

// ------------------------------------------------------------------- scan ---
// Persistent GRU scan, plain launch, 64 WGs x 4 waves, WG owns 16 hidden cols.
// Step structure keeps ALL HBM traffic (deferred out-stores, gx prefetch) at
// the TOP of the step so the pre-barrier vmcnt(0) only waits on the fresh
// LLC h-store acks. h is exchanged through the LLC via agent-scope relaxed
// atomics; per-step barrier is a fence-free monotonic counter.
template <int LAYER>
__global__ __launch_bounds__(256, 1) void scan_kernel(
    const u16* __restrict__ gx,    // gxoff layout (b_ih folded in)
    const u16* __restrict__ whh,   // [3072*1024] bf16 row-major
    const float* __restrict__ bhh, // [3072] fp32
    u16* __restrict__ hbuf,        // [2*65536] fragment layout (ping=idx0 init)
    u16* __restrict__ out_bf,      // LAYER==0: out0 bf16 row-major
    float* __restrict__ out_f,     // LAYER==1: d_out fp32
    float* __restrict__ hN,        // final h (fp32, 64*1024)
    u32* __restrict__ bar)         // barrier counter (zeroed by convert)
{
  extern __shared__ u16 wlds[];    // 49152 u16 = 96 KB
  const int tid = threadIdx.x;
  const int lane = tid & 63;
  const int wave = tid >> 6;       // row-tile (16 batch rows)
  const int bx = blockIdx.x;
  const int jbase = bx * 16;
  const int jr = lane & 15;

  // ---- one-time: W_hh slice -> LDS in fragment order ----
  #pragma unroll
  for (int u = 0; u < 24; ++u) {
    const int idx = wave * 24 + u;           // 0..95 = ct*32+ks
    const int ct = idx >> 5, ks = idx & 31;
    const int wrow = ct * 1024 + jbase + jr;
    const int k = ks * 32 + ((lane >> 4) << 3);
    *(bf16x8*)(wlds + idx * 512 + lane * 8) =
        *(const bf16x8*)(whh + (size_t)wrow * 1024 + k);
  }
  __syncthreads();

  const int j = jbase + jr;
  const float bias_r = bhh[j], bias_z = bhh[1024 + j], bias_n = bhh[2048 + j];

  // double-buffered gx registers: px = step t (in use), nx = step t+1 (filling)
  float pxr[4], pxz[4], pxn[4], nxr[4], nxz[4], nxn[4];
  {
    const u16* g = gx + gxoff(0, bx, 0, 0, 0);
    #pragma unroll
    for (int r = 0; r < 4; ++r) {
      const int b = wave * 16 + ((lane >> 4) << 2) + r;
      pxr[r] = bf2f(g[b * 16 + jr]);
      pxz[r] = bf2f(g[1024 + b * 16 + jr]);
      pxn[r] = bf2f(g[2048 + b * 16 + jr]);
    }
  }

  // deferred output state (stored at the top of the NEXT step)
  u16 hu_prev[4] = {0, 0, 0, 0};
  float hv_prev[4] = {0.f, 0.f, 0.f, 0.f};

  int p = 0;
  for (int t = 0; t < 512; ++t) {
    // (A) deferred HBM out-store for step t-1 — issued early, acks age a
    //     full compute phase before the next vmcnt(0)
    if (t > 0) {
      #pragma unroll
      for (int r = 0; r < 4; ++r) {
        const int b = wave * 16 + ((lane >> 4) << 2) + r;
        const size_t orow = (size_t)(t - 1) * 64 + b;
        if (LAYER == 0) __builtin_nontemporal_store(hu_prev[r], out_bf + orow * 1024 + j);
        else            __builtin_nontemporal_store(hv_prev[r], out_f + orow * 1024 + j);
      }
    }
    // (C) gx prefetch for step t+1 (HBM) — issued at step top, covered by MFMA
    if (t < 511) {
      const u16* g = gx + gxoff(t + 1, bx, 0, 0, 0);
      #pragma unroll
      for (int r = 0; r < 4; ++r) {
        const int b = wave * 16 + ((lane >> 4) << 2) + r;
        nxr[r] = bf2f(g[b * 16 + jr]);
        nxz[r] = bf2f(g[1024 + b * 16 + jr]);
        nxn[r] = bf2f(g[2048 + b * 16 + jr]);
      }
    }

    // (B) h loads from LLC
    const u16* hsrc = hbuf + p * 65536;
    const u16* ab = hsrc + wave * 16384 + lane * 8;
    bf16x8 a[32];
    #pragma unroll
    for (int ks = 0; ks < 32; ++ks)
      a[ks] = h_load128(ab + ks * 512);          // coherent 16B loads (LLC)

    float ho[4];
    #pragma unroll
    for (int r = 0; r < 4; ++r) {
      const int b = wave * 16 + ((lane >> 4) << 2) + r;
      ho[r] = bf2f(h_load16(hsrc + fragoff(b, j)));
    }

    // (D) MFMA
    f32x4 accr = {0.f, 0.f, 0.f, 0.f};
    f32x4 accz = accr, accn = accr;
    #pragma unroll
    for (int ks = 0; ks < 32; ++ks) {
      bf16x8 b0 = *(const bf16x8*)(wlds + ks * 512 + lane * 8);
      bf16x8 b1 = *(const bf16x8*)(wlds + (32 + ks) * 512 + lane * 8);
      bf16x8 b2 = *(const bf16x8*)(wlds + (64 + ks) * 512 + lane * 8);
      accr = MFMA_BF16(a[ks], b0, accr, 0, 0, 0);
      accz = MFMA_BF16(a[ks], b1, accz, 0, 0, 0);
      accn = MFMA_BF16(a[ks], b2, accn, 0, 0, 0);
    }

    // (E) gates; h_store to LLC (the only young vmem op at the barrier)
    u16* hdst = hbuf + (p ^ 1) * 65536;
    #pragma unroll
    for (int r = 0; r < 4; ++r) {
      const int b = wave * 16 + ((lane >> 4) << 2) + r;
      const float rg = 1.f / (1.f + __expf(-(pxr[r] + accr[r] + bias_r)));
      const float zg = 1.f / (1.f + __expf(-(pxz[r] + accz[r] + bias_z)));
      const float ng = tanhf(pxn[r] + rg * (accn[r] + bias_n));
      const float hv = (1.f - zg) * ng + zg * ho[r];
      const u16 hu = f2bf(hv);
      h_store(hdst + fragoff(b, j), hu);
      hu_prev[r] = hu; hv_prev[r] = hv;
    }

    // (F) fence-free grid barrier (skipped after the last step)
    if (t < 511) {
      asm volatile("s_waitcnt vmcnt(0)" ::: "memory");  // h stores performed
      __syncthreads();
      if (tid == 0) {
        __hip_atomic_fetch_add(bar, 1u, __ATOMIC_RELAXED, __HIP_MEMORY_SCOPE_AGENT);
        const u32 tgt = 64u * (u32)(t + 1);
        while (__hip_atomic_load(bar, __ATOMIC_RELAXED, __HIP_MEMORY_SCOPE_AGENT) < tgt)
          __builtin_amdgcn_s_sleep(1);
      }
      __syncthreads();
    }

    #pragma unroll
    for (int r = 0; r < 4; ++r) { pxr[r] = nxr[r]; pxz[r] = nxz[r]; pxn[r] = nxn[r]; }
    p ^= 1;
  }

  // epilogue: final-step output + h_n (ordered by kernel-end flush)
  #pragma unroll
  for (int r = 0; r < 4; ++r) {
    const int b = wave * 16 + ((lane >> 4) << 2) + r;
    const size_t orow = (size_t)511 * 64 + b;
    if (LAYER == 0) __builtin_nontemporal_store(hu_prev[r], out_bf + orow * 1024 + j);
    else            __builtin_nontemporal_store(hv_prev[r], out_f + orow * 1024 + j);
    __builtin_nontemporal_store(hv_prev[r], hN + b * 1024 + j);
  }
}

// ----------------------------------------------------------------- launch ---
extern "C" void kernel_launch(void* const* d_in, const int* in_sizes, int n_in,
                              void* d_out, int out_size, void* d_ws, size_t ws_size,
                              hipStream_t stream)
{
  const float* x     = (const float*)d_in[0];
  const float* h0    = (const float*)d_in[1];
  const float* w_ih0 = (const float*)d_in[2];
  const float* w_hh0 = (const float*)d_in[3];
  const float* b_ih0 = (const float*)d_in[4];
  const float* b_hh0 = (const float*)d_in[5];
  const float* w_ih1 = (const float*)d_in[6];
  const float* w_hh1 = (const float*)d_in[7];
  const float* b_ih1 = (const float*)d_in[8];
  const float* b_hh1 = (const float*)d_in[9];

  if (ws_size < 294125824ull) return;   // insufficient scratch -> fail visibly

  char* ws = (char*)d_ws;
  u16* xb   = (u16*)(ws + 0);           // x bf16; later reused as out0
  u16* out0 = xb;                       // alias: xb dead after first GEMM
  u16* gx   = (u16*)(ws + 67108864);
  u16* wb   = (u16*)(ws + 268435456);
  u16* hb0  = (u16*)(ws + 293601280);
  u16* hb1  = (u16*)(ws + 293863424);
  u32* bar  = (u32*)(ws + 294125568);

  float* out1 = (float*)d_out;
  float* hN0  = out1 + 33554432;        // h_n[0]
  float* hN1  = hN0 + 65536;            // h_n[1]

  u16* wb_ih0 = wb;
  u16* wb_hh0 = wb + 3145728;
  u16* wb_ih1 = wb + 6291456;
  u16* wb_hh1 = wb + 9437184;

  hipLaunchKernelGGL(convert_kernel, dim3(1024), dim3(256), 0, stream,
                     x, w_ih0, w_hh0, w_ih1, w_hh1, h0, xb, wb, hb0, hb1, bar);

  dim3 gg(256, 24);
  hipLaunchKernelGGL(gemm_bt_bias, gg, dim3(256), 0, stream, xb, wb_ih0, b_ih0, gx);

  hipFuncSetAttribute(reinterpret_cast<const void*>(&scan_kernel<0>),
                      hipFuncAttributeMaxDynamicSharedMemorySize, 98304);
  hipFuncSetAttribute(reinterpret_cast<const void*>(&scan_kernel<1>),
                      hipFuncAttributeMaxDynamicSharedMemorySize, 98304);

  hipLaunchKernelGGL(scan_kernel<0>, dim3(64), dim3(256), 98304, stream,
                     (const u16*)gx, (const u16*)wb_hh0, b_hh0,
                     hb0, out0, (float*)nullptr, hN0, bar);

  hipLaunchKernelGGL(gemm_bt_bias, gg, dim3(256), 0, stream, out0, wb_ih1, b_ih1, gx);

  hipLaunchKernelGGL(scan_kernel<1>, dim3(64), dim3(256), 98304, stream,
                     (const u16*)gx, (const u16*)wb_hh1, b_hh1,
                     hb1, (u16*)nullptr, out1, hN1, bar + 32);
}